// Round 5
// baseline (57.989 us; speedup 1.0000x reference)
//
#include <hip/hip_runtime.h>
#include <hip/hip_bf16.h>

#define NWS 16
#define ZD 512
#define MM 100
#define NCOL 112             // padded col count (7 x 16)
#define HALF_BYTES 57344     // 112 cols * 256 k * 2 B
#define PANEL_BYTES 114688   // 112 cols * 512 k * 2 B

typedef __attribute__((ext_vector_type(8))) short bf16x8;
typedef __attribute__((ext_vector_type(4))) float f32x4;

static __device__ __forceinline__ unsigned short f2bf(float x) {
    union { __hip_bfloat16 h; unsigned short u; } cv;
    cv.h = __float2bfloat16(x);
    return cv.u;
}

// ---------------- Kernel 0: basis fp32 [w][k][ij] -> bf16 swizzled panel
// Bt[w][half][col][k] with byte swizzle ((col&7)<<4) XOR'd into the k-offset,
// so a linear LDS copy yields conflict-free ds_read_b128 fragments.
__global__ __launch_bounds__(256) void prep_basis(const float* __restrict__ basis,
                                                  unsigned char* __restrict__ Bt) {
    const int idx = blockIdx.x * 256 + threadIdx.x;   // 16*64*112 = 114688
    const int col  = idx % NCOL;
    const int rest = idx / NCOL;
    const int g    = rest & 63;        // k-group of 8
    const int w    = rest >> 6;

    bf16x8 pk;
    #pragma unroll
    for (int e = 0; e < 8; ++e) {
        const int k = g * 8 + e;
        const float v = (col < MM) ? basis[((size_t)(w * ZD + k)) * MM + col] : 0.f;
        pk[e] = (short)f2bf(v);
    }
    const int half = g >> 5;
    const int gl   = g & 31;
    const size_t off = (size_t)w * PANEL_BYTES + (size_t)half * HALF_BYTES
                     + (size_t)col * 512 + (size_t)((gl * 16) ^ ((col & 7) << 4));
    *reinterpret_cast<bf16x8*>(Bt + off) = pk;
}

// ---------------- Kernel A: lie_alg = z @ basis via bf16 MFMA, B panel in LDS
// grid (16, 32), block 512 (8 waves, 16 rows each = 128 rows/block)
// 4-deep z register prefetch; B staged via async global_load_lds (width 16).
__global__ __launch_bounds__(512, 4) void einsum_mfma(const float* __restrict__ z,
                                                      const unsigned char* __restrict__ Btg,
                                                      float* __restrict__ out) {
    __shared__ __align__(16) unsigned char Bs[HALF_BYTES];
    const int w     = blockIdx.x;
    const int chunk = blockIdx.y;
    const int tid   = threadIdx.x;
    const int wave  = tid >> 6;
    const int lane  = tid & 63;
    const int l15   = lane & 15;
    const int k8    = lane >> 4;

    const int row = chunk * 128 + wave * 16 + l15;
    const float* zp = z + (size_t)row * (NWS * ZD) + (size_t)w * ZD + k8 * 8;
    const unsigned char* bt = Btg + (size_t)w * PANEL_BYTES;

    int bbase[7];
    #pragma unroll
    for (int nf = 0; nf < 7; ++nf) bbase[nf] = (nf * 16 + l15) * 512;
    const int bswz = (l15 & 7) << 4;

    f32x4 acc[7];
    #pragma unroll
    for (int nf = 0; nf < 7; ++nf) acc[nf] = (f32x4){0.f, 0.f, 0.f, 0.f};

    // ---- 4-deep z prefetch ring (static indices only)
    float4 za[4][2];
    #pragma unroll
    for (int s = 0; s < 4; ++s) {
        za[s][0] = *reinterpret_cast<const float4*>(zp + s * 32);
        za[s][1] = *reinterpret_cast<const float4*>(zp + s * 32 + 4);
    }

    #pragma unroll
    for (int half = 0; half < 2; ++half) {
        if (half) __syncthreads();         // all waves done reading previous panel
        // ---- async stage half-panel: linear lane*16 copy (swizzle pre-baked in global)
        {
            const unsigned char* g = bt + half * HALF_BYTES + tid * 16;
            #pragma unroll
            for (int i = 0; i < 7; ++i) {
                __builtin_amdgcn_global_load_lds(
                    (const __attribute__((address_space(1))) unsigned int*)(g + i * 8192),
                    (__attribute__((address_space(3))) unsigned int*)(&Bs[i * 8192 + tid * 16]),
                    16, 0, 0);
            }
        }
        __syncthreads();                   // drains staging (and in-flight z prefetch)

        #pragma unroll
        for (int step = 0; step < 8; ++step) {
            const int gs = half * 8 + step;   // compile-time (both loops unrolled)
            const int sl = gs & 3;
            bf16x8 af;
            af[0] = (short)f2bf(za[sl][0].x);
            af[1] = (short)f2bf(za[sl][0].y);
            af[2] = (short)f2bf(za[sl][0].z);
            af[3] = (short)f2bf(za[sl][0].w);
            af[4] = (short)f2bf(za[sl][1].x);
            af[5] = (short)f2bf(za[sl][1].y);
            af[6] = (short)f2bf(za[sl][1].z);
            af[7] = (short)f2bf(za[sl][1].w);
            if (gs + 4 < 16) {                // refill ring slot
                za[sl][0] = *reinterpret_cast<const float4*>(zp + (gs + 4) * 32);
                za[sl][1] = *reinterpret_cast<const float4*>(zp + (gs + 4) * 32 + 4);
            }
            const int klb = (step * 64 + k8 * 16) ^ bswz;
            #pragma unroll
            for (int nf = 0; nf < 7; ++nf) {
                const bf16x8 bfr = *reinterpret_cast<const bf16x8*>(Bs + bbase[nf] + klb);
                acc[nf] = __builtin_amdgcn_mfma_f32_16x16x32_bf16(af, bfr, acc[nf], 0, 0, 0);
            }
        }
    }

    // C layout: col = lane&15, row = (lane>>4)*4 + r  (verified R2/R3)
    const int rowbase = chunk * 128 + wave * 16 + k8 * 4;
    #pragma unroll
    for (int nf = 0; nf < 7; ++nf) {
        const int col = nf * 16 + l15;
        if (col < MM) {
            #pragma unroll
            for (int r = 0; r < 4; ++r)
                out[((size_t)(rowbase + r) * NWS + w) * MM + col] = acc[nf][r];
        }
    }
}

// ---------------- Kernel B: in-place expm of 10x10 matrices
// block 320 = 64 matrices x 5 threads; thread owns 2 columns; A in registers
// (STATIC indexing only — init columns read from LDS to avoid scratch demotion).
#define EXP_NT 6

__global__ __launch_bounds__(320, 2) void expm_kernel(float* __restrict__ out) {
    __shared__ float As[64 * 100];
    const int t = threadIdx.x;
    const size_t base = (size_t)blockIdx.x * 6400;

    #pragma unroll
    for (int q = 0; q < 5; ++q) {
        const int idx = (q * 320 + t) * 4;
        *reinterpret_cast<float4*>(&As[idx]) =
            *reinterpret_cast<const float4*>(out + base + idx);
    }
    __syncthreads();

    const int m  = t / 5;
    const int c  = t - m * 5;
    const int j0 = 2 * c, j1 = j0 + 1;
    const float* A = &As[m * 100];

    float a[100];                          // statically indexed ONLY -> registers
    #pragma unroll
    for (int q = 0; q < 25; ++q) {
        const float4 v = *reinterpret_cast<const float4*>(A + q * 4);
        a[q * 4 + 0] = v.x; a[q * 4 + 1] = v.y;
        a[q * 4 + 2] = v.z; a[q * 4 + 3] = v.w;
    }

    // init: P = I + A/N — columns j0,j1 read from LDS (runtime index OK there)
    float p0[10], p1[10];
    #pragma unroll
    for (int i = 0; i < 10; ++i) {
        p0[i] = A[i * 10 + j0] * (1.f / EXP_NT) + ((i == j0) ? 1.f : 0.f);
        p1[i] = A[i * 10 + j1] * (1.f / EXP_NT) + ((i == j1) ? 1.f : 0.f);
    }

    #pragma unroll
    for (int k = EXP_NT - 1; k >= 1; --k) {
        float n0[10], n1[10];
        #pragma unroll
        for (int i = 0; i < 10; ++i) { n0[i] = 0.f; n1[i] = 0.f; }
        #pragma unroll
        for (int kk = 0; kk < 10; ++kk) {
            const float q0 = p0[kk], q1 = p1[kk];
            #pragma unroll
            for (int i = 0; i < 10; ++i) {
                n0[i] = fmaf(a[i * 10 + kk], q0, n0[i]);
                n1[i] = fmaf(a[i * 10 + kk], q1, n1[i]);
            }
        }
        const float invk = 1.f / (float)k;
        #pragma unroll
        for (int i = 0; i < 10; ++i) {
            p0[i] = n0[i] * invk + ((i == j0) ? 1.f : 0.f);
            p1[i] = n1[i] * invk + ((i == j1) ? 1.f : 0.f);
        }
    }

    #pragma unroll
    for (int i = 0; i < 10; ++i)
        *reinterpret_cast<float2*>(out + base + m * 100 + i * 10 + j0) =
            make_float2(p0[i], p1[i]);
}

extern "C" void kernel_launch(void* const* d_in, const int* in_sizes, int n_in,
                              void* d_out, int out_size, void* d_ws, size_t ws_size,
                              hipStream_t stream) {
    const float* z     = (const float*)d_in[0];   // [4096,16,512]
    const float* basis = (const float*)d_in[1];   // [16,512,10,10]
    float* out = (float*)d_out;                   // [4096,16,10,10]
    unsigned char* Bt = (unsigned char*)d_ws;     // 16 * 114688 B = 1.83 MB

    prep_basis<<<(NWS * 64 * NCOL) / 256, 256, 0, stream>>>(basis, Bt);

    dim3 gridA(NWS, 32);
    einsum_mfma<<<gridA, 512, 0, stream>>>(z, Bt, out);

    expm_kernel<<<(4096 * NWS) / 64, 320, 0, stream>>>(out);
}